// Round 16
// baseline (437.596 us; speedup 1.0000x reference)
//
#include <hip/hip_runtime.h>
#include <hip/hip_bf16.h>

#define B_ 4
#define N_ 2048
#define F_ 256
#define H_ 8
#define O_ 256

// log2(e)/16 folded into Q so softmax can use exp2f (exact softmax, monotone map)
#define SCALE_QK 0.09016844005556021f

typedef __attribute__((ext_vector_type(8))) short short8;
typedef __attribute__((ext_vector_type(4))) short s16x4;
typedef __attribute__((ext_vector_type(4))) float f32x4;
typedef __attribute__((ext_vector_type(4))) unsigned int u32x4;

static __device__ __forceinline__ float bf2f(short u) {
    unsigned int x = ((unsigned int)(unsigned short)u) << 16;
    return __builtin_bit_cast(float, x);
}
static __device__ __forceinline__ short f2bf(float f) {
    unsigned int x = __builtin_bit_cast(unsigned int, f);
    unsigned int lsb = (x >> 16) & 1u;
    x += 0x7fffu + lsb;
    return (short)(x >> 16);
}
// packed f32x2 -> bf16x2 in one instruction (RNE); no builtin on gfx950
static __device__ __forceinline__ unsigned int cvtpk(float a, float b) {
    unsigned int r;
    asm("v_cvt_pk_bf16_f32 %0, %1, %2" : "=v"(r) : "v"(a), "v"(b));
    return r;
}

// async global->LDS 16B/lane; LDS dst is wave-uniform base + lane*16
static __device__ __forceinline__ void gld16(const short* g, short* l) {
    __builtin_amdgcn_global_load_lds(
        (const __attribute__((address_space(1))) void*)g,
        (__attribute__((address_space(3))) void*)l, 16, 0, 0);
}

// ---- f32 -> bf16 transpose (+ optional straight copy): dstT[c][r] = dst2[r][c] = bf16(src[r][c])
__global__ __launch_bounds__(256) void cvtT_kernel(const float* __restrict__ src,
                                                   short* __restrict__ dstT,
                                                   short* __restrict__ dst2,
                                                   int R, int C) {
    __shared__ short tile[32][33];
    src  += (size_t)blockIdx.z * R * C;
    dstT += (size_t)blockIdx.z * R * C;
    if (dst2) dst2 += (size_t)blockIdx.z * R * C;
    int tx = threadIdx.x, ty = threadIdx.y;           // 32 x 8
    int c0 = blockIdx.x * 32, r0 = blockIdx.y * 32;
#pragma unroll
    for (int j = 0; j < 4; j++) {
        int r = r0 + ty + j * 8;
        short v = f2bf(src[(size_t)r * C + c0 + tx]);
        tile[ty + j * 8][tx] = v;
        if (dst2) dst2[(size_t)r * C + c0 + tx] = v;
    }
    __syncthreads();
#pragma unroll
    for (int j = 0; j < 4; j++) {
        int c = c0 + ty + j * 8;
        dstT[(size_t)c * R + r0 + tx] = tile[tx][ty + j * 8];
    }
}

// ====== out GEMM: out[m][o] = msgs[m][:2048] @ Wout + bias (R7-verified) ======
__global__ __launch_bounds__(512) void out_kernel(const short* __restrict__ msgs,
                                                  const short* __restrict__ WoutT,
                                                  const float* __restrict__ bias,
                                                  float* __restrict__ out) {
    __shared__ short sA[2][64 * 64];    // 8 KB x2: [64 m][8 chunks of 8 k]
    __shared__ short sB[2][128 * 64];   // 16 KB x2: [128 n][8 chunks of 8 k]
    int mt = blockIdx.x, nt = blockIdx.y;
    int tid = threadIdx.x, w = tid >> 6, l = tid & 63, lq = l & 15, quad = l >> 4;
    const short* Arow = msgs  + (size_t)(mt * 64)  * (H_ * F_);
    const short* Brow = WoutT + (size_t)(nt * 128) * (H_ * F_);
    int xk = (l & 7) ^ (l >> 3);   // pre-swizzled source chunk (row%8 == l>>3)

    f32x4 acc[4];
#pragma unroll
    for (int i = 0; i < 4; i++) acc[i] = (f32x4)(0.f);

#define STAGE_OUT(KB, BI) do {                                               \
        gld16(&Arow[(size_t)(w * 8 + (l >> 3)) * (H_ * F_) + (KB) * 64 + xk * 8], \
              &sA[BI][w * 8 * 64]);                                          \
        gld16(&Brow[(size_t)(w * 16 + (l >> 3)) * (H_ * F_) + (KB) * 64 + xk * 8], \
              &sB[BI][w * 16 * 64]);                                         \
        gld16(&Brow[(size_t)(w * 16 + 8 + (l >> 3)) * (H_ * F_) + (KB) * 64 + xk * 8], \
              &sB[BI][(w * 16 + 8) * 64]);                                   \
    } while (0)

    STAGE_OUT(0, 0);
    __syncthreads();

#pragma unroll 1
    for (int kb = 0; kb < 32; kb++) {
        int cur = kb & 1;
        if (kb < 31) STAGE_OUT(kb + 1, cur ^ 1);
        int arow = (w & 3) * 16 + lq;
#pragma unroll
        for (int kk = 0; kk < 2; kk++) {
            short8 af = *(const short8*)&sA[cur][arow * 64 + (((kk * 4 + quad) ^ (arow & 7)) * 8)];
#pragma unroll
            for (int ct = 0; ct < 4; ct++) {
                int brow = (w >> 2) * 64 + ct * 16 + lq;
                short8 bf = *(const short8*)&sB[cur][brow * 64 + (((kk * 4 + quad) ^ (brow & 7)) * 8)];
                acc[ct] = __builtin_amdgcn_mfma_f32_16x16x32_bf16(af, bf, acc[ct], 0, 0, 0);
            }
        }
        __syncthreads();
    }

#pragma unroll
    for (int ct = 0; ct < 4; ct++) {
        int gcol = nt * 128 + (w >> 2) * 64 + ct * 16 + lq;
        float bv = bias[gcol];
#pragma unroll
        for (int r = 0; r < 4; r++) {
            int row = mt * 64 + (w & 3) * 16 + quad * 4 + r;
            out[(size_t)row * O_ + gcol] = acc[ct][r] + bv;
        }
    }
}

// ============ fused flash attention, 16 waves x 16 q (4 waves/SIMD) ============
// R16: 1024-thread block covering 256 q; grid (8,32) = 256 blocks = 1/CU,
// all-resident single lockstep pass. Motivation (R14): kernel is LATENCY-
// bound and waves/SIMD is the dominant lever (2->1 cost 30%); this doubles
// it to 4 with per-wave phase-1 code BYTE-IDENTICAL to the verified
// optimum (oacc[16]+aq[8] ~ 104 VGPR <= 128-VGPR cap at 4 waves/SIMD, so
// the R8/R12 spill mechanism does not apply). Per-CU totals of LDS/MFMA/
// VALU/staging unchanged; K/V sweep demand per CU HALVES (one sweep per
// 256 q); barrier count per CU halves (32 tile-phases vs 64).
// Phase 0 runs as two half-passes of the verified structure with an
// f-split: wave w computes q-group (w&7), f-half (w>>3); Q transits LDS
// as before; aq read guarded by (w>>3)==half.
// Pre-committed reads: WRITE >> 40 MB => spill -> revert R13;
// FETCH >> 60 MB clean-WRITE => 256-block cache-hostile -> revert R13.

// stage key-tile KT: K rows into KVF [64][256] (XOR b^(r&31)),
// V^T rows into KVTF [256][64] (XOR b^(r&7)); 16 waves, 4 gld16/lane.
#define STAGE_KV(KT, KVF, KVTF) do {                                         \
    _Pragma("unroll")                                                        \
    for (int i_ = 0; i_ < 2; i_++) {                                         \
        int rk_ = w * 4 + i_ * 2 + (l >> 5);                                 \
        int bk_ = (l & 31) ^ (rk_ & 31);                                     \
        gld16(&Xb[(size_t)((KT) * 64 + rk_) * F_ + bk_ * 8],                 \
              &KVF[(w * 4 + i_ * 2) * 256]);                                 \
        int rt_ = w * 16 + i_ * 8 + (l >> 3);                                \
        int bt_ = (l & 7) ^ (rt_ & 7);                                       \
        gld16(&XTb[(size_t)rt_ * N_ + (KT) * 64 + bt_ * 8],                  \
              &KVTF[(w * 16 + i_ * 8) * 64]);                                \
    }                                                                        \
} while (0)

// per-wave compute: verified byte-identical body (uses lq/quad/aq/m_q/l_q/oacc only)
#define COMPUTE_KT(KVF, KVTF) do {                                           \
    f32x4 sacc[4];                                                           \
    _Pragma("unroll")                                                        \
    for (int ct = 0; ct < 4; ct++) sacc[ct] = (f32x4)(0.f);                  \
    __builtin_amdgcn_s_setprio(1);                                           \
    _Pragma("unroll")                                                        \
    for (int kk = 0; kk < 8; kk++) {                                         \
        _Pragma("unroll")                                                    \
        for (int ct = 0; ct < 4; ct++) {                                     \
            int arow = ct * 16 + lq;                                         \
            int ab = (kk * 4 + quad) ^ (arow & 31);                          \
            short8 af = *(const short8*)&KVF[arow * 256 + ab * 8];           \
            sacc[ct] = __builtin_amdgcn_mfma_f32_16x16x32_bf16(af, aq[kk], sacc[ct], 0, 0, 0); \
        }                                                                    \
    }                                                                        \
    __builtin_amdgcn_s_setprio(0);                                           \
    float mx = -INFINITY;                                                    \
    _Pragma("unroll")                                                        \
    for (int ct = 0; ct < 4; ct++)                                           \
        _Pragma("unroll")                                                    \
        for (int r_ = 0; r_ < 4; r_++) mx = fmaxf(mx, sacc[ct][r_]);         \
    mx = fmaxf(mx, __shfl_xor(mx, 16));                                      \
    mx = fmaxf(mx, __shfl_xor(mx, 32));                                      \
    if (!__all(mx - m_q <= 8.0f)) {      /* T13 defer-max, THR=8 */          \
        float mn = fmaxf(m_q, mx);                                           \
        float alpha = exp2f(m_q - mn);                                       \
        m_q = mn;                                                            \
        l_q *= alpha;                                                        \
        _Pragma("unroll")                                                    \
        for (int ct = 0; ct < 16; ct++)                                      \
            _Pragma("unroll")                                                \
            for (int r_ = 0; r_ < 4; r_++) oacc[ct][r_] *= alpha;            \
    }                                                                        \
    float pv[4][4]; float s_ = 0.f;                                          \
    _Pragma("unroll")                                                        \
    for (int ct = 0; ct < 4; ct++)                                           \
        _Pragma("unroll")                                                    \
        for (int r_ = 0; r_ < 4; r_++) {                                     \
            pv[ct][r_] = exp2f(sacc[ct][r_] - m_q);                          \
            s_ += pv[ct][r_];                                                \
        }                                                                    \
    s_ += __shfl_xor(s_, 16);                                                \
    s_ += __shfl_xor(s_, 32);                                                \
    l_q += s_;                                                               \
    unsigned int w2[4][2];                                                   \
    _Pragma("unroll")                                                        \
    for (int ct = 0; ct < 4; ct++) {                                         \
        w2[ct][0] = cvtpk(pv[ct][0], pv[ct][1]);                             \
        w2[ct][1] = cvtpk(pv[ct][2], pv[ct][3]);                             \
    }                                                                        \
    int sl0 = (2 * (quad & 1)) * 16 + lq;                                    \
    int sl1 = sl0 + 16;                                                      \
    bool hi = (quad >> 1) != 0;                                              \
    short8 pfrag[2];                                                         \
    _Pragma("unroll")                                                        \
    for (int kk = 0; kk < 2; kk++) {                                         \
        unsigned int u0 = __shfl((int)w2[2 * kk][0], sl0);                   \
        unsigned int u1 = __shfl((int)w2[2 * kk][1], sl0);                   \
        unsigned int u2 = __shfl((int)w2[2 * kk][0], sl1);                   \
        unsigned int u3 = __shfl((int)w2[2 * kk][1], sl1);                   \
        unsigned int v0 = __shfl((int)w2[2 * kk + 1][0], sl0);               \
        unsigned int v1 = __shfl((int)w2[2 * kk + 1][1], sl0);               \
        unsigned int v2 = __shfl((int)w2[2 * kk + 1][0], sl1);               \
        unsigned int v3 = __shfl((int)w2[2 * kk + 1][1], sl1);               \
        u32x4 pk = { hi ? v0 : u0, hi ? v1 : u1, hi ? v2 : u2, hi ? v3 : u3 }; \
        pfrag[kk] = __builtin_bit_cast(short8, pk);                          \
    }                                                                        \
    __builtin_amdgcn_s_setprio(1);                                           \
    _Pragma("unroll")                                                        \
    for (int ct = 0; ct < 16; ct++) {                                        \
        int arow = ct * 16 + lq;                                             \
        short8 a0 = *(const short8*)&KVTF[arow * 64 + ((quad) ^ (arow & 7)) * 8]; \
        short8 a1 = *(const short8*)&KVTF[arow * 64 + ((4 + quad) ^ (arow & 7)) * 8]; \
        oacc[ct] = __builtin_amdgcn_mfma_f32_16x16x32_bf16(a0, pfrag[0], oacc[ct], 0, 0, 0); \
        oacc[ct] = __builtin_amdgcn_mfma_f32_16x16x32_bf16(a1, pfrag[1], oacc[ct], 0, 0, 0); \
    }                                                                        \
    __builtin_amdgcn_s_setprio(0);                                           \
} while (0)

__global__ __launch_bounds__(1024) void attn_kernel(const short* __restrict__ X,
                                                    const short* __restrict__ WhT,
                                                    const short* __restrict__ XT,
                                                    short* __restrict__ msgs) {
    __shared__ short kvfA[64 * 256];    // 32 KB
    __shared__ short kvfB[64 * 256];    // 32 KB
    __shared__ short kvTfA[256 * 64];   // 32 KB
    __shared__ short kvTfB[256 * 64];   // 32 KB

    int qt = blockIdx.x, bh = blockIdx.y, b = bh >> 3, h = bh & 7;
    int tid = threadIdx.x, w = tid >> 6, l = tid & 63, lq = l & 15, quad = l >> 4;
    int q0 = qt * 256;
    int g = w & 7;          // q-group within a 128-row half
    int fh = w >> 3;        // f-half (phase 0) / q-half owner (aq)

    const short* Xb  = X  + (size_t)b * N_ * F_;
    const short* XTb = XT + (size_t)b * F_ * N_;
    const short* Whh = WhT + (size_t)h * F_ * F_;

    f32x4 oacc[16];
    short8 aq[8];

    // ---------- phase 0: Q = (X qtile @ Wh) * SCALE_QK, two 128-row halves ----
    // Half hp: X rows q0+hp*128..+127 staged (waves 0-7 -> kvfA, 8-15 -> kvfB);
    // W streamed through kvTfA in 64-wide chunks; wave w computes q-group g,
    // f-cols fh*128..+127 (oacc[0..7]); Q written to kvTfA/B; aq read by the
    // waves whose q rows live in this half (fh == hp).
#pragma unroll 1
    for (int hp = 0; hp < 2; hp++) {
        {   // stage X: wave w stages 8 rows (4 issues x 2 rows)
            short* xdst = (w < 8) ? kvfA : kvfB;
#pragma unroll
            for (int i = 0; i < 4; i++) {
                int rl = g * 8 + i * 2 + (l >> 5);           // local row in buffer
                int bb = (l & 31) ^ (rl & 31);
                gld16(&Xb[(size_t)(q0 + hp * 128 + fh * 64 + rl) * F_ + bb * 8],
                      &xdst[(g * 8 + i * 2) * 256]);
            }
        }
#pragma unroll
        for (int i = 0; i < 8; i++) oacc[i] = (f32x4)(0.f);
        const short* xsrc = (g < 4) ? kvfA : kvfB;           // rows 0-63 / 64-127
        int arowl = (g & 3) * 16 + lq;
#pragma unroll 1
        for (int kb = 0; kb < 4; kb++) {
            __syncthreads();   // prev chunk's W reads (and prev half's aq reads) done
#pragma unroll
            for (int i = 0; i < 2; i++) {   // stage WhT[h][0:256][kb*64..+63] -> kvTfA
                int rt = w * 16 + i * 8 + (l >> 3);
                int bt = (l & 7) ^ (rt & 7);
                gld16(&Whh[(size_t)rt * F_ + kb * 64 + bt * 8], &kvTfA[(w * 16 + i * 8) * 64]);
            }
            __syncthreads();   // drains DMA (X on kb==0, W always)
#pragma unroll
            for (int kk = 0; kk < 2; kk++) {
                int ab = (kb * 8 + kk * 4 + quad) ^ (arowl & 31);
                short8 af = *(const short8*)&xsrc[arowl * 256 + ab * 8];
#pragma unroll
                for (int ct = 0; ct < 8; ct++) {
                    int brow = fh * 128 + ct * 16 + lq;
                    int bb = (kk * 4 + quad) ^ (brow & 7);
                    short8 bf = *(const short8*)&kvTfA[brow * 64 + bb * 8];
                    oacc[ct] = __builtin_amdgcn_mfma_f32_16x16x32_bf16(af, bf, oacc[ct], 0, 0, 0);
                }
            }
        }
        __syncthreads();   // all W reads done; write Q rows 0-63 -> kvTfA, 64-127 -> kvTfB
        {
            short* qdst = (g < 4) ? kvTfA : kvTfB;
#pragma unroll
            for (int ct = 0; ct < 8; ct++) {
#pragma unroll
                for (int r = 0; r < 4; r++) {
                    int rl = (g & 3) * 16 + quad * 4 + r;
                    int col = fh * 128 + ct * 16 + lq;
                    int pb = (col >> 3) ^ (rl & 31);
                    qdst[rl * 256 + pb * 8 + (col & 7)] = f2bf(oacc[ct][r] * SCALE_QK);
                }
            }
            __syncthreads();
            if (fh == hp) {   // this wave's q rows (q0 + w*16) live in this half
                const short* qsrc = (g < 4) ? kvTfA : kvTfB;
                int rl = (g & 3) * 16 + lq;
#pragma unroll
                for (int kk = 0; kk < 8; kk++) {
                    int ab = (kk * 4 + quad) ^ (rl & 31);
                    aq[kk] = *(const short8*)&qsrc[rl * 256 + ab * 8];
                }
            }
        }
    }
    __syncthreads();   // all aq reads done before tile-0 DMA overwrites buffers

    // ---------- phase 1: pipelined flash attention (verified loop shape) ----------
#pragma unroll
    for (int i = 0; i < 16; i++) oacc[i] = (f32x4)(0.f);
    float m_q = -INFINITY, l_q = 0.f;   // state for q = q0 + w*16 + lq

    STAGE_KV(0, kvfA, kvTfA);
    __syncthreads();   // drain tile-0 DMA

#pragma unroll 1
    for (int kt2 = 0; kt2 < 16; kt2++) {
        // half A: prefetch tile 2*kt2+1 -> B pair, compute from A pair
        STAGE_KV(2 * kt2 + 1, kvfB, kvTfB);
        COMPUTE_KT(kvfA, kvTfA);
        __syncthreads();   // all A-reads done + B-prefetch (issued pre-compute) drained
        // half B: prefetch tile (2*kt2+2)&31 -> A pair, compute from B pair
        STAGE_KV((2 * kt2 + 2) & 31, kvfA, kvTfA);   // last iter refetches tile 0 (unused, harmless)
        COMPUTE_KT(kvfB, kvTfB);
        __syncthreads();
    }

    // epilogue: per-lane q = q0 + w*16 + lq; feats ct*16 + quad*4 + r
    float inv = 1.f / l_q;
    short* Mout = msgs + (size_t)(b * N_ + q0 + w * 16 + lq) * (H_ * F_) + h * F_;
#pragma unroll
    for (int ct = 0; ct < 16; ct++) {
        s16x4 v4 = { f2bf(oacc[ct][0] * inv), f2bf(oacc[ct][1] * inv),
                     f2bf(oacc[ct][2] * inv), f2bf(oacc[ct][3] * inv) };
        *(s16x4*)&Mout[ct * 16 + quad * 4] = v4;
    }
}

extern "C" void kernel_launch(void* const* d_in, const int* in_sizes, int n_in,
                              void* d_out, int out_size, void* d_ws, size_t ws_size,
                              hipStream_t stream) {
    const float* nodes = (const float*)d_in[0];   // [4,2048,256] f32
    const float* Wh    = (const float*)d_in[1];   // [8,256,256]  f32
    const float* Wout  = (const float*)d_in[2];   // [2048,256]   f32
    const float* bias  = (const float*)d_in[3];   // [256]        f32
    float* out = (float*)d_out;                   // [4,2048,256] f32

    char* ws = (char*)d_ws;
    short* msgs   = (short*)(ws);                   // [8192][2048] bf16 = 32 MB
    short* WhT    = (short*)(ws + 33554432);        // [8][256][256]       1 MB
    short* WoutT  = (short*)(ws + 34603008);        // [256][2048]         1 MB
    short* XT     = (short*)(ws + 35651584);        // [4][256][2048]      4 MB
    short* Xbf    = (short*)(ws + 39845888);        // [4][2048][256]      4 MB

    dim3 tblk(32, 8, 1);
    hipLaunchKernelGGL(cvtT_kernel, dim3(8, 8, 8),  tblk, 0, stream, Wh,    WhT,   (short*)nullptr, 256,  256);
    hipLaunchKernelGGL(cvtT_kernel, dim3(8, 64, 1), tblk, 0, stream, Wout,  WoutT, (short*)nullptr, 2048, 256);
    hipLaunchKernelGGL(cvtT_kernel, dim3(8, 64, 4), tblk, 0, stream, nodes, XT,    Xbf,             2048, 256);

    hipLaunchKernelGGL(attn_kernel, dim3(8, 32), dim3(1024), 0, stream, Xbf, WhT, XT, msgs);
    hipLaunchKernelGGL(out_kernel,  dim3(128, 2), dim3(512), 0, stream, msgs, WoutT, bias, out);
}